// Round 1
// baseline (1490.338 us; speedup 1.0000x reference)
//
#include <hip/hip_runtime.h>

#define NN 100000
#define NE 1600000
#define DD 128

typedef __attribute__((ext_vector_type(8))) short bf16x8;
typedef __attribute__((ext_vector_type(4))) float f32x4;

__device__ __forceinline__ float bf2f(unsigned short u){
  union { unsigned int i; float f; } v; v.i = ((unsigned int)u) << 16; return v.f;
}
__device__ __forceinline__ unsigned short f2bf(float f){
  union { float f; unsigned int i; } v; v.f = f;
  unsigned int u = v.i;
  return (unsigned short)((u + 0x7fffu + ((u >> 16) & 1u)) >> 16);
}
__device__ __forceinline__ unsigned int cvt_pk_bf16(float lo, float hi){
  unsigned int r;
  asm("v_cvt_pk_bf16_f32 %0, %1, %2" : "=v"(r) : "v"(lo), "v"(hi));
  return r;
}

// ---------- weight f32 -> bf16 (one 128x128 matrix = 8192 float2) ----------
__global__ __launch_bounds__(256) void cvt_w(const float* __restrict__ w,
                                             unsigned short* __restrict__ o){
  int t = blockIdx.x * 256 + threadIdx.x;           // 8192 threads
  if (t < 8192){
    float2 v = ((const float2*)w)[t];
    ((unsigned int*)o)[t] = cvt_pk_bf16(v.x, v.y);
  }
}

// ---------- CSR build ----------
__global__ __launch_bounds__(256) void count_deg(const int* __restrict__ dst,
                                                 int* __restrict__ deg, int n){
  int t = blockIdx.x * 256 + threadIdx.x;
  if (t < n) atomicAdd(&deg[dst[t]], 1);
}

#define SCAN_CHUNK 1024
__global__ __launch_bounds__(256) void partial_sums(const int* __restrict__ deg,
                                                    int* __restrict__ partials, int n){
  __shared__ int lds[256];
  int t = threadIdx.x;
  int base = blockIdx.x * SCAN_CHUNK + t * 4;
  int s = 0;
  #pragma unroll
  for (int i = 0; i < 4; ++i){ int idx = base + i; s += (idx < n) ? deg[idx] : 0; }
  lds[t] = s; __syncthreads();
  for (int off = 128; off > 0; off >>= 1){
    if (t < off) lds[t] += lds[t + off];
    __syncthreads();
  }
  if (t == 0) partials[blockIdx.x] = lds[0];
}

__global__ void scan_partials(int* partials, int nb){
  if (threadIdx.x == 0 && blockIdx.x == 0){
    int acc = 0;
    for (int i = 0; i < nb; ++i){ int v = partials[i]; partials[i] = acc; acc += v; }
  }
}

__global__ __launch_bounds__(256) void scan_block(const int* __restrict__ deg,
                                                  const int* __restrict__ partials,
                                                  int* __restrict__ row_start, int n){
  __shared__ int lds[256];
  int t = threadIdx.x;
  int base = blockIdx.x * SCAN_CHUNK + t * 4;
  int v[4]; int s = 0;
  #pragma unroll
  for (int i = 0; i < 4; ++i){ int idx = base + i; v[i] = (idx < n) ? deg[idx] : 0; s += v[i]; }
  lds[t] = s; __syncthreads();
  for (int off = 1; off < 256; off <<= 1){
    int x = (t >= off) ? lds[t - off] : 0;
    __syncthreads();
    lds[t] += x;
    __syncthreads();
  }
  int excl = ((t == 0) ? 0 : lds[t - 1]) + partials[blockIdx.x];
  #pragma unroll
  for (int i = 0; i < 4; ++i){ int idx = base + i; if (idx < n) row_start[idx] = excl; excl += v[i]; }
}

__global__ __launch_bounds__(256) void fill_csr(const int* __restrict__ src,
                                                const int* __restrict__ dst,
                                                const int* __restrict__ row_start,
                                                int* __restrict__ cursor,
                                                int* __restrict__ csr, int n){
  int t = blockIdx.x * 256 + threadIdx.x;
  if (t < n){
    int d = dst[t];
    int pos = atomicAdd(&cursor[d], 1);
    csr[row_start[d] + pos] = src[t];
  }
}

// ---------- h0 = bf16(item_emb[x]) ----------
__global__ __launch_bounds__(256) void gather_h0(const int* __restrict__ x,
                                                 const float* __restrict__ emb,
                                                 unsigned short* __restrict__ h, int n){
  int t = blockIdx.x * 256 + threadIdx.x;          // n*64 threads, 2 feats each
  if (t >= n * 64) return;
  int node = t >> 6, p = t & 63;
  int s = x[node];
  float2 v = *(const float2*)(emb + (size_t)s * DD + p * 2);
  ((unsigned int*)h)[t] = cvt_pk_bf16(v.x, v.y);
}

// ---------- mean aggregation: one wave per node, 2 feats per lane ----------
__global__ __launch_bounds__(256) void aggregate(const unsigned short* __restrict__ h,
                                                 const int* __restrict__ csr,
                                                 const int* __restrict__ row_start,
                                                 const int* __restrict__ deg,
                                                 unsigned short* __restrict__ mean, int n){
  int node = blockIdx.x * 4 + (threadIdx.x >> 6);
  if (node >= n) return;
  int lane = threadIdx.x & 63;
  int start = row_start[node];
  int d = deg[node];
  const unsigned int* hp = (const unsigned int*)h;
  float s0 = 0.f, s1 = 0.f;
  for (int i = 0; i < d; ++i){
    int srcn = csr[start + i];
    unsigned int v = hp[(size_t)srcn * 64 + lane];
    s0 += bf2f((unsigned short)(v & 0xffffu));
    s1 += bf2f((unsigned short)(v >> 16));
  }
  float inv = 1.0f / fmaxf((float)d, 1.0f);
  ((unsigned int*)mean)[(size_t)node * 64 + lane] = cvt_pk_bf16(s0 * inv, s1 * inv);
}

// ---------- fused node GEMM: out = relu(A1@B1^T (+ A2@B2^T) + bias) ----------
// per wave: 16 rows x 128 cols; block 256 -> 64 rows
template<int DUAL, int OUTF32>
__global__ __launch_bounds__(256) void gemm_node(
    const unsigned short* __restrict__ A1, const unsigned short* __restrict__ B1,
    const unsigned short* __restrict__ A2, const unsigned short* __restrict__ B2,
    const float* __restrict__ bias, void* __restrict__ outp, int M)
{
  int wave = threadIdx.x >> 6, lane = threadIdx.x & 63;
  int r0 = blockIdx.x * 64 + wave * 16;
  if (r0 >= M) return;
  int lr = lane & 15, lk = lane >> 4;
  f32x4 acc[8];
  #pragma unroll
  for (int j = 0; j < 8; ++j) acc[j] = (f32x4){0.f, 0.f, 0.f, 0.f};

  {
    const unsigned short* Ap = A1 + (size_t)(r0 + lr) * DD + lk * 8;
    const unsigned short* Bp = B1 + (size_t)lr * DD + lk * 8;
    #pragma unroll
    for (int ks = 0; ks < 4; ++ks){
      bf16x8 a = *(const bf16x8*)(Ap + ks * 32);
      #pragma unroll
      for (int j = 0; j < 8; ++j){
        bf16x8 b = *(const bf16x8*)(Bp + j * 16 * DD + ks * 32);
        acc[j] = __builtin_amdgcn_mfma_f32_16x16x32_bf16(a, b, acc[j], 0, 0, 0);
      }
    }
  }
  if (DUAL){
    const unsigned short* Ap = A2 + (size_t)(r0 + lr) * DD + lk * 8;
    const unsigned short* Bp = B2 + (size_t)lr * DD + lk * 8;
    #pragma unroll
    for (int ks = 0; ks < 4; ++ks){
      bf16x8 a = *(const bf16x8*)(Ap + ks * 32);
      #pragma unroll
      for (int j = 0; j < 8; ++j){
        bf16x8 b = *(const bf16x8*)(Bp + j * 16 * DD + ks * 32);
        acc[j] = __builtin_amdgcn_mfma_f32_16x16x32_bf16(a, b, acc[j], 0, 0, 0);
      }
    }
  }
  #pragma unroll
  for (int j = 0; j < 8; ++j){
    int col = j * 16 + lr;
    float bv = bias[col];
    #pragma unroll
    for (int r = 0; r < 4; ++r){
      size_t row = (size_t)r0 + lk * 4 + r;
      float v = fmaxf(acc[j][r] + bv, 0.f);
      if (OUTF32) ((float*)outp)[row * DD + col] = v;
      else        ((unsigned short*)outp)[row * DD + col] = f2bf(v);
    }
  }
}

// ---------- edge GEMM: out = relu(A_f32 @ B^T + bias), A converted inline ----------
__global__ __launch_bounds__(256) void gemm_edge(
    const float* __restrict__ A, const unsigned short* __restrict__ B,
    const float* __restrict__ bias, float* __restrict__ out, int M)
{
  int wave = threadIdx.x >> 6, lane = threadIdx.x & 63;
  int r0 = blockIdx.x * 64 + wave * 16;   // M divisible by 64
  int lr = lane & 15, lk = lane >> 4;
  f32x4 acc[8];
  #pragma unroll
  for (int j = 0; j < 8; ++j) acc[j] = (f32x4){0.f, 0.f, 0.f, 0.f};

  const float* Ap = A + (size_t)(r0 + lr) * DD + lk * 8;
  const unsigned short* Bp = B + (size_t)lr * DD + lk * 8;
  #pragma unroll
  for (int ks = 0; ks < 4; ++ks){
    f32x4 a0 = *(const f32x4*)(Ap + ks * 32);
    f32x4 a1 = *(const f32x4*)(Ap + ks * 32 + 4);
    union { bf16x8 v; unsigned int u[4]; } au;
    au.u[0] = cvt_pk_bf16(a0[0], a0[1]);
    au.u[1] = cvt_pk_bf16(a0[2], a0[3]);
    au.u[2] = cvt_pk_bf16(a1[0], a1[1]);
    au.u[3] = cvt_pk_bf16(a1[2], a1[3]);
    #pragma unroll
    for (int j = 0; j < 8; ++j){
      bf16x8 b = *(const bf16x8*)(Bp + j * 16 * DD + ks * 32);
      acc[j] = __builtin_amdgcn_mfma_f32_16x16x32_bf16(au.v, b, acc[j], 0, 0, 0);
    }
  }
  #pragma unroll
  for (int j = 0; j < 8; ++j){
    int col = j * 16 + lr;
    float bv = bias[col];
    #pragma unroll
    for (int r = 0; r < 4; ++r){
      size_t row = (size_t)r0 + lk * 4 + r;
      out[row * DD + col] = fmaxf(acc[j][r] + bv, 0.f);
    }
  }
}

extern "C" void kernel_launch(void* const* d_in, const int* in_sizes, int n_in,
                              void* d_out, int out_size, void* d_ws, size_t ws_size,
                              hipStream_t stream)
{
  const int*   x    = (const int*)d_in[0];
  const int*   ei   = (const int*)d_in[1];
  const int*   srcp = ei;
  const int*   dstp = ei + NE;
  const float* item = (const float*)d_in[3];
  const float* eemb = (const float*)d_in[4];
  const float* Wf[8] = {
    (const float*)d_in[5],  // Wl1
    (const float*)d_in[7],  // Wr1
    (const float*)d_in[8],  // Wl2
    (const float*)d_in[10], // Wr2
    (const float*)d_in[11], // Wl3
    (const float*)d_in[13], // Wr3
    (const float*)d_in[14], // W_lin1
    (const float*)d_in[16]  // W_lin2
  };
  const float* bl1 = (const float*)d_in[6];
  const float* bl2 = (const float*)d_in[9];
  const float* bl3 = (const float*)d_in[12];
  const float* bq1 = (const float*)d_in[15];
  const float* bq2 = (const float*)d_in[17];

  char* ws = (char*)d_ws;
  size_t o = 0;
  auto alloc = [&](size_t bytes) -> void* {
    void* p = ws + o;
    o += (bytes + 255) & ~(size_t)255;
    return p;
  };
  unsigned short* wbf      = (unsigned short*)alloc(8 * 16384 * 2);
  int*            deg      = (int*)alloc((size_t)NN * 4);
  int*            cursor   = (int*)alloc((size_t)NN * 4);
  int*            row_st   = (int*)alloc((size_t)NN * 4);
  int*            partials = (int*)alloc(4096);
  int*            csr      = (int*)alloc((size_t)NE * 4);
  unsigned short* mean     = (unsigned short*)alloc((size_t)NN * DD * 2);
  unsigned short* h_a      = (unsigned short*)alloc((size_t)NN * DD * 2);
  unsigned short* h_b      = (unsigned short*)alloc((size_t)NN * DD * 2);

  float* out_h = (float*)d_out;
  float* out_e = out_h + (size_t)NN * DD;

  // zero deg + cursor (adjacent allocations, each padded to 256B)
  hipMemsetAsync(deg, 0, ((size_t)NN * 4 + 255 & ~(size_t)255) * 2, stream);

  for (int m = 0; m < 8; ++m)
    cvt_w<<<32, 256, 0, stream>>>(Wf[m], wbf + m * 16384);

  const int nb = (NN + SCAN_CHUNK - 1) / SCAN_CHUNK;      // 98
  count_deg<<<(NE + 255) / 256, 256, 0, stream>>>(dstp, deg, NE);
  partial_sums<<<nb, 256, 0, stream>>>(deg, partials, NN);
  scan_partials<<<1, 64, 0, stream>>>(partials, nb);
  scan_block<<<nb, 256, 0, stream>>>(deg, partials, row_st, NN);
  fill_csr<<<(NE + 255) / 256, 256, 0, stream>>>(srcp, dstp, row_st, cursor, csr, NE);

  gather_h0<<<(NN * 64 + 255) / 256, 256, 0, stream>>>(x, item, h_a, NN);

  const int agg_grid  = (NN + 3) / 4;
  const int node_grid = (NN + 63) / 64;

  // layer 1: h_a -> h_b
  aggregate<<<agg_grid, 256, 0, stream>>>(h_a, csr, row_st, deg, mean, NN);
  gemm_node<1,0><<<node_grid, 256, 0, stream>>>(mean, wbf + 0*16384, h_a, wbf + 1*16384, bl1, h_b, NN);
  // layer 2: h_b -> h_a
  aggregate<<<agg_grid, 256, 0, stream>>>(h_b, csr, row_st, deg, mean, NN);
  gemm_node<1,0><<<node_grid, 256, 0, stream>>>(mean, wbf + 2*16384, h_b, wbf + 3*16384, bl2, h_a, NN);
  // layer 3: h_a -> h_b
  aggregate<<<agg_grid, 256, 0, stream>>>(h_a, csr, row_st, deg, mean, NN);
  gemm_node<1,0><<<node_grid, 256, 0, stream>>>(mean, wbf + 4*16384, h_a, wbf + 5*16384, bl3, h_b, NN);

  // final node linear -> f32 out
  gemm_node<0,1><<<node_grid, 256, 0, stream>>>(h_b, wbf + 6*16384, h_b, wbf + 6*16384, bq1, out_h, NN);

  // edge linear -> f32 out
  gemm_edge<<<NE / 64, 256, 0, stream>>>(eemb, wbf + 7*16384, bq2, out_e, NE);
}

// Round 2
// 864.640 us; speedup vs baseline: 1.7237x; 1.7237x over previous
//
#include <hip/hip_runtime.h>

#define NN  100000
#define NNP 100096   // NN padded to multiple of 128
#define NE  1600000
#define DD  128

typedef __attribute__((ext_vector_type(8))) short bf16x8;
typedef __attribute__((ext_vector_type(4))) float f32x4;

__device__ __forceinline__ float bf2f(unsigned short u){
  union { unsigned int i; float f; } v; v.i = ((unsigned int)u) << 16; return v.f;
}
__device__ __forceinline__ unsigned short f2bf(float f){
  union { float f; unsigned int i; } v; v.f = f;
  unsigned int u = v.i;
  return (unsigned short)((u + 0x7fffu + ((u >> 16) & 1u)) >> 16);
}
__device__ __forceinline__ unsigned int cvt_pk_bf16(float lo, float hi){
  unsigned int r;
  asm("v_cvt_pk_bf16_f32 %0, %1, %2" : "=v"(r) : "v"(lo), "v"(hi));
  return r;
}

// ---------- all 8 weight matrices f32 -> bf16 in one launch ----------
struct WPtrs { const float* w[8]; };
__global__ __launch_bounds__(256) void cvt_w_all(WPtrs wp, unsigned short* __restrict__ o){
  int t = blockIdx.x * 256 + threadIdx.x;     // 65536 threads
  int m = t >> 13, i = t & 8191;
  float2 v = ((const float2*)wp.w[m])[i];
  ((unsigned int*)o)[t] = cvt_pk_bf16(v.x, v.y);
}

// ---------- CSR build ----------
__global__ __launch_bounds__(256) void count_deg(const int* __restrict__ dst,
                                                 int* __restrict__ deg, int n){
  int t = blockIdx.x * 256 + threadIdx.x;
  if (t < n) atomicAdd(&deg[dst[t]], 1);
}

#define SCAN_CHUNK 1024
__global__ __launch_bounds__(256) void partial_sums(const int* __restrict__ deg,
                                                    int* __restrict__ partials, int n){
  __shared__ int lds[256];
  int t = threadIdx.x;
  int base = blockIdx.x * SCAN_CHUNK + t * 4;
  int s = 0;
  #pragma unroll
  for (int i = 0; i < 4; ++i){ int idx = base + i; s += (idx < n) ? deg[idx] : 0; }
  lds[t] = s; __syncthreads();
  for (int off = 128; off > 0; off >>= 1){
    if (t < off) lds[t] += lds[t + off];
    __syncthreads();
  }
  if (t == 0) partials[blockIdx.x] = lds[0];
}

__global__ void scan_partials(int* partials, int nb){
  if (threadIdx.x == 0 && blockIdx.x == 0){
    int acc = 0;
    for (int i = 0; i < nb; ++i){ int v = partials[i]; partials[i] = acc; acc += v; }
  }
}

__global__ __launch_bounds__(256) void scan_block(const int* __restrict__ deg,
                                                  const int* __restrict__ partials,
                                                  int* __restrict__ row_start, int n){
  __shared__ int lds[256];
  int t = threadIdx.x;
  int base = blockIdx.x * SCAN_CHUNK + t * 4;
  int v[4]; int s = 0;
  #pragma unroll
  for (int i = 0; i < 4; ++i){ int idx = base + i; v[i] = (idx < n) ? deg[idx] : 0; s += v[i]; }
  lds[t] = s; __syncthreads();
  for (int off = 1; off < 256; off <<= 1){
    int x = (t >= off) ? lds[t - off] : 0;
    __syncthreads();
    lds[t] += x;
    __syncthreads();
  }
  int excl = ((t == 0) ? 0 : lds[t - 1]) + partials[blockIdx.x];
  #pragma unroll
  for (int i = 0; i < 4; ++i){ int idx = base + i; if (idx < n) row_start[idx] = excl; excl += v[i]; }
}

__global__ __launch_bounds__(256) void fill_csr(const int* __restrict__ src,
                                                const int* __restrict__ dst,
                                                const int* __restrict__ row_start,
                                                int* __restrict__ cursor,
                                                int* __restrict__ csr, int n){
  int t = blockIdx.x * 256 + threadIdx.x;
  if (t < n){
    int d = dst[t];
    int pos = atomicAdd(&cursor[d], 1);
    csr[row_start[d] + pos] = src[t];
  }
}

// ---------- h0 = bf16(item_emb[x]) ----------
__global__ __launch_bounds__(256) void gather_h0(const int* __restrict__ x,
                                                 const float* __restrict__ emb,
                                                 unsigned short* __restrict__ h, int n){
  int t = blockIdx.x * 256 + threadIdx.x;          // n*64 threads, 2 feats each
  if (t >= n * 64) return;
  int node = t >> 6, p = t & 63;
  int s = x[node];
  float2 v = *(const float2*)(emb + (size_t)s * DD + p * 2);
  ((unsigned int*)h)[t] = cvt_pk_bf16(v.x, v.y);
}

// ---------- mean aggregation: one wave per node, 4 neighbors in flight ----------
__global__ __launch_bounds__(256) void aggregate2(const unsigned short* __restrict__ h,
                                                  const int* __restrict__ csr,
                                                  const int* __restrict__ row_start,
                                                  const int* __restrict__ deg,
                                                  unsigned short* __restrict__ mean, int n){
  int node = blockIdx.x * 4 + (threadIdx.x >> 6);
  if (node >= n) return;
  int lane = threadIdx.x & 63;
  int st = row_start[node];
  int d = deg[node];
  const unsigned int* hp = (const unsigned int*)h;
  float s0 = 0.f, s1 = 0.f, t0 = 0.f, t1 = 0.f;
  float u0 = 0.f, u1 = 0.f, w0 = 0.f, w1 = 0.f;
  int i = 0;
  for (; i + 4 <= d; i += 4){
    int n0 = csr[st + i], n1 = csr[st + i + 1], n2 = csr[st + i + 2], n3 = csr[st + i + 3];
    unsigned int v0 = hp[(size_t)n0 * 64 + lane];
    unsigned int v1 = hp[(size_t)n1 * 64 + lane];
    unsigned int v2 = hp[(size_t)n2 * 64 + lane];
    unsigned int v3 = hp[(size_t)n3 * 64 + lane];
    s0 += bf2f((unsigned short)(v0 & 0xffffu)); s1 += bf2f((unsigned short)(v0 >> 16));
    t0 += bf2f((unsigned short)(v1 & 0xffffu)); t1 += bf2f((unsigned short)(v1 >> 16));
    u0 += bf2f((unsigned short)(v2 & 0xffffu)); u1 += bf2f((unsigned short)(v2 >> 16));
    w0 += bf2f((unsigned short)(v3 & 0xffffu)); w1 += bf2f((unsigned short)(v3 >> 16));
  }
  for (; i < d; ++i){
    int s = csr[st + i];
    unsigned int v = hp[(size_t)s * 64 + lane];
    s0 += bf2f((unsigned short)(v & 0xffffu)); s1 += bf2f((unsigned short)(v >> 16));
  }
  s0 += t0 + u0 + w0;
  s1 += t1 + u1 + w1;
  float inv = 1.0f / fmaxf((float)d, 1.0f);
  ((unsigned int*)mean)[(size_t)node * 64 + lane] = cvt_pk_bf16(s0 * inv, s1 * inv);
}

// ---------- stage one 128x128 bf16 matrix into LDS, k-chunk-major ----------
// layout: sB[(kc*128 + col)*8 .. +8] holds W[col][kc*8 .. kc*8+8]
// fragment read (ks,j,lane): addr = ((ks*4+lk)*128 + j*16+lr)*16B -> bank-uniform
__device__ __forceinline__ void stage_mat(const unsigned short* __restrict__ Bg,
                                          unsigned short* sB){
  int t = threadIdx.x; // 256
  #pragma unroll
  for (int it = 0; it < 8; ++it){
    int idx = it * 256 + t;               // 0..2047 = kc*128 + col
    int kc = idx >> 7, col = idx & 127;
    uint4 v = *(const uint4*)(Bg + (size_t)col * DD + kc * 8);
    *(uint4*)(sB + (size_t)idx * 8) = v;
  }
}

// ---------- edge GEMM: out = relu(A_f32 @ W^T + b), LDS-staged W ----------
__global__ __launch_bounds__(256) void gemm_edge2(
    const float* __restrict__ A, const unsigned short* __restrict__ Bg,
    const float* __restrict__ bias, float* __restrict__ out, int ntiles)
{
  __shared__ unsigned short sB[16384]; // 32KB
  stage_mat(Bg, sB);
  __syncthreads();
  int wave = threadIdx.x >> 6, lane = threadIdx.x & 63;
  int lr = lane & 15, lk = lane >> 4;
  float bv[8];
  #pragma unroll
  for (int j = 0; j < 8; ++j) bv[j] = bias[j * 16 + lr];

  for (int tile = blockIdx.x; tile < ntiles; tile += gridDim.x){
    size_t r0 = (size_t)tile * 128 + wave * 32;
    const float* Ap = A + (r0 + lr) * DD + lk * 8;
    bf16x8 a[2][4];
    #pragma unroll
    for (int g = 0; g < 2; ++g){
      #pragma unroll
      for (int ks = 0; ks < 4; ++ks){
        f32x4 a0 = *(const f32x4*)(Ap + (size_t)g * 16 * DD + ks * 32);
        f32x4 a1 = *(const f32x4*)(Ap + (size_t)g * 16 * DD + ks * 32 + 4);
        union { bf16x8 v; unsigned int u[4]; } au;
        au.u[0] = cvt_pk_bf16(a0[0], a0[1]);
        au.u[1] = cvt_pk_bf16(a0[2], a0[3]);
        au.u[2] = cvt_pk_bf16(a1[0], a1[1]);
        au.u[3] = cvt_pk_bf16(a1[2], a1[3]);
        a[g][ks] = au.v;
      }
    }
    f32x4 acc[2][8];
    #pragma unroll
    for (int g = 0; g < 2; ++g)
      #pragma unroll
      for (int j = 0; j < 8; ++j) acc[g][j] = (f32x4){0.f, 0.f, 0.f, 0.f};
    #pragma unroll
    for (int ks = 0; ks < 4; ++ks){
      #pragma unroll
      for (int j = 0; j < 8; ++j){
        bf16x8 b = *(const bf16x8*)(sB + ((ks * 4 + lk) * 128 + j * 16 + lr) * 8);
        acc[0][j] = __builtin_amdgcn_mfma_f32_16x16x32_bf16(a[0][ks], b, acc[0][j], 0, 0, 0);
        acc[1][j] = __builtin_amdgcn_mfma_f32_16x16x32_bf16(a[1][ks], b, acc[1][j], 0, 0, 0);
      }
    }
    #pragma unroll
    for (int g = 0; g < 2; ++g)
      #pragma unroll
      for (int j = 0; j < 8; ++j)
        #pragma unroll
        for (int r = 0; r < 4; ++r){
          size_t row = r0 + g * 16 + lk * 4 + r;
          out[row * DD + j * 16 + lr] = fmaxf(acc[g][j][r] + bv[j], 0.f);
        }
  }
}

// ---------- node GEMM: out = relu(A1@B1^T (+A2@B2^T) + b), LDS-staged ----------
template<int DUAL, int OUTF32>
__global__ __launch_bounds__(256) void gemm_node2(
    const unsigned short* __restrict__ A1, const unsigned short* __restrict__ B1g,
    const unsigned short* __restrict__ A2, const unsigned short* __restrict__ B2g,
    const float* __restrict__ bias, void* __restrict__ outp, int M, int ntiles)
{
  __shared__ unsigned short sB[DUAL ? 32768 : 16384];
  stage_mat(B1g, sB);
  if (DUAL) stage_mat(B2g, sB + 16384);
  __syncthreads();
  int wave = threadIdx.x >> 6, lane = threadIdx.x & 63;
  int lr = lane & 15, lk = lane >> 4;
  float bv[8];
  #pragma unroll
  for (int j = 0; j < 8; ++j) bv[j] = bias[j * 16 + lr];

  for (int tile = blockIdx.x; tile < ntiles; tile += gridDim.x){
    size_t r0 = (size_t)tile * 128 + wave * 32;
    f32x4 acc[2][8];
    #pragma unroll
    for (int g = 0; g < 2; ++g)
      #pragma unroll
      for (int j = 0; j < 8; ++j) acc[g][j] = (f32x4){0.f, 0.f, 0.f, 0.f};

    {
      const unsigned short* Ap = A1 + (r0 + lr) * DD + lk * 8;
      bf16x8 a[2][4];
      #pragma unroll
      for (int g = 0; g < 2; ++g)
        #pragma unroll
        for (int ks = 0; ks < 4; ++ks)
          a[g][ks] = *(const bf16x8*)(Ap + (size_t)g * 16 * DD + ks * 32);
      #pragma unroll
      for (int ks = 0; ks < 4; ++ks){
        #pragma unroll
        for (int j = 0; j < 8; ++j){
          bf16x8 b = *(const bf16x8*)(sB + ((ks * 4 + lk) * 128 + j * 16 + lr) * 8);
          acc[0][j] = __builtin_amdgcn_mfma_f32_16x16x32_bf16(a[0][ks], b, acc[0][j], 0, 0, 0);
          acc[1][j] = __builtin_amdgcn_mfma_f32_16x16x32_bf16(a[1][ks], b, acc[1][j], 0, 0, 0);
        }
      }
    }
    if (DUAL){
      const unsigned short* Ap = A2 + (r0 + lr) * DD + lk * 8;
      bf16x8 a[2][4];
      #pragma unroll
      for (int g = 0; g < 2; ++g)
        #pragma unroll
        for (int ks = 0; ks < 4; ++ks)
          a[g][ks] = *(const bf16x8*)(Ap + (size_t)g * 16 * DD + ks * 32);
      #pragma unroll
      for (int ks = 0; ks < 4; ++ks){
        #pragma unroll
        for (int j = 0; j < 8; ++j){
          bf16x8 b = *(const bf16x8*)(sB + 16384 + ((ks * 4 + lk) * 128 + j * 16 + lr) * 8);
          acc[0][j] = __builtin_amdgcn_mfma_f32_16x16x32_bf16(a[0][ks], b, acc[0][j], 0, 0, 0);
          acc[1][j] = __builtin_amdgcn_mfma_f32_16x16x32_bf16(a[1][ks], b, acc[1][j], 0, 0, 0);
        }
      }
    }
    #pragma unroll
    for (int g = 0; g < 2; ++g)
      #pragma unroll
      for (int j = 0; j < 8; ++j)
        #pragma unroll
        for (int r = 0; r < 4; ++r){
          size_t row = r0 + g * 16 + lk * 4 + r;
          float v = fmaxf(acc[g][j][r] + bv[j], 0.f);
          if (OUTF32){
            if (row < (size_t)M) ((float*)outp)[row * DD + j * 16 + lr] = v;
          } else {
            ((unsigned short*)outp)[row * DD + j * 16 + lr] = f2bf(v);
          }
        }
  }
}

extern "C" void kernel_launch(void* const* d_in, const int* in_sizes, int n_in,
                              void* d_out, int out_size, void* d_ws, size_t ws_size,
                              hipStream_t stream)
{
  const int*   x    = (const int*)d_in[0];
  const int*   ei   = (const int*)d_in[1];
  const int*   srcp = ei;
  const int*   dstp = ei + NE;
  const float* item = (const float*)d_in[3];
  const float* eemb = (const float*)d_in[4];
  WPtrs wp;
  wp.w[0] = (const float*)d_in[5];  // Wl1
  wp.w[1] = (const float*)d_in[7];  // Wr1
  wp.w[2] = (const float*)d_in[8];  // Wl2
  wp.w[3] = (const float*)d_in[10]; // Wr2
  wp.w[4] = (const float*)d_in[11]; // Wl3
  wp.w[5] = (const float*)d_in[13]; // Wr3
  wp.w[6] = (const float*)d_in[14]; // W_lin1
  wp.w[7] = (const float*)d_in[16]; // W_lin2
  const float* bl1 = (const float*)d_in[6];
  const float* bl2 = (const float*)d_in[9];
  const float* bl3 = (const float*)d_in[12];
  const float* bq1 = (const float*)d_in[15];
  const float* bq2 = (const float*)d_in[17];

  char* ws = (char*)d_ws;
  size_t o = 0;
  auto alloc = [&](size_t bytes) -> void* {
    void* p = ws + o;
    o += (bytes + 255) & ~(size_t)255;
    return p;
  };
  unsigned short* wbf      = (unsigned short*)alloc(8 * 16384 * 2);
  int*            deg      = (int*)alloc((size_t)NN * 4);
  int*            cursor   = (int*)alloc((size_t)NN * 4);
  int*            row_st   = (int*)alloc((size_t)NN * 4);
  int*            partials = (int*)alloc(4096);
  int*            csr      = (int*)alloc((size_t)NE * 4);
  unsigned short* mean     = (unsigned short*)alloc((size_t)NNP * DD * 2);
  unsigned short* h_a      = (unsigned short*)alloc((size_t)NNP * DD * 2);
  unsigned short* h_b      = (unsigned short*)alloc((size_t)NNP * DD * 2);

  float* out_h = (float*)d_out;
  float* out_e = out_h + (size_t)NN * DD;

  // zero deg + cursor (adjacent allocations, each padded to 256B)
  hipMemsetAsync(deg, 0, (((size_t)NN * 4 + 255) & ~(size_t)255) * 2, stream);

  cvt_w_all<<<256, 256, 0, stream>>>(wp, wbf);

  const int nb = (NN + SCAN_CHUNK - 1) / SCAN_CHUNK;      // 98
  count_deg<<<(NE + 255) / 256, 256, 0, stream>>>(dstp, deg, NE);
  partial_sums<<<nb, 256, 0, stream>>>(deg, partials, NN);
  scan_partials<<<1, 64, 0, stream>>>(partials, nb);
  scan_block<<<nb, 256, 0, stream>>>(deg, partials, row_st, NN);
  fill_csr<<<(NE + 255) / 256, 256, 0, stream>>>(srcp, dstp, row_st, cursor, csr, NE);

  gather_h0<<<(NN * 64 + 255) / 256, 256, 0, stream>>>(x, item, h_a, NN);

  const int agg_grid   = (NN + 3) / 4;
  const int node_tiles = NNP / 128;         // 782
  const int edge_tiles = NE / 128;          // 12500

  // layer 1: h_a -> h_b
  aggregate2<<<agg_grid, 256, 0, stream>>>(h_a, csr, row_st, deg, mean, NN);
  gemm_node2<1,0><<<node_tiles, 256, 0, stream>>>(mean, wbf + 0*16384, h_a, wbf + 1*16384, bl1, h_b, NN, node_tiles);
  // layer 2: h_b -> h_a
  aggregate2<<<agg_grid, 256, 0, stream>>>(h_b, csr, row_st, deg, mean, NN);
  gemm_node2<1,0><<<node_tiles, 256, 0, stream>>>(mean, wbf + 2*16384, h_b, wbf + 3*16384, bl2, h_a, NN, node_tiles);
  // layer 3: h_a -> h_b
  aggregate2<<<agg_grid, 256, 0, stream>>>(h_a, csr, row_st, deg, mean, NN);
  gemm_node2<1,0><<<node_tiles, 256, 0, stream>>>(mean, wbf + 4*16384, h_a, wbf + 5*16384, bl3, h_b, NN, node_tiles);

  // final node linear -> f32 out (guarded stores at M)
  gemm_node2<0,1><<<node_tiles, 256, 0, stream>>>(h_b, wbf + 6*16384, h_b, wbf + 6*16384, bq1, out_h, NN, node_tiles);

  // edge linear -> f32 out
  gemm_edge2<<<2500, 256, 0, stream>>>(eemb, wbf + 7*16384, bq2, out_e, edge_tiles);
}